// Round 4
// baseline (563.615 us; speedup 1.0000x reference)
//
#include <hip/hip_runtime.h>

// Problem constants
#define M_TOT   16384      // 8*2048 rows
#define DM      1024       // d_model
#define CD      64         // code_depth
#define NCODES  8192
#define NCHUNK  16         // code-chunks for dist/argmin
#define CPC     (NCODES / NCHUNK)   // 512 codes per chunk
#define CTILE   16         // codes per register tile

// Output layout (fp32, concatenated in return order)
#define SOFT_OFF  0
#define IDX_OFF   1048576            // 16384*64
#define HARD_OFF  1064960            // + 16384
#define LOSS_OFF  2113536            // + 16384*64

// ---------------------------------------------------------------------------
// Kernel 0: c2[k] = ||book_k||^2
// ---------------------------------------------------------------------------
__global__ __launch_bounds__(256) void compute_c2(const float* __restrict__ book,
                                                  float* __restrict__ c2) {
    const int k = blockIdx.x * 256 + threadIdx.x;
    const float4* p = (const float4*)(book + (size_t)k * CD);
    float s = 0.0f;
#pragma unroll
    for (int q = 0; q < CD / 4; ++q) {
        const float4 v = p[q];
        s = fmaf(v.x, v.x, s);
        s = fmaf(v.y, v.y, s);
        s = fmaf(v.z, v.z, s);
        s = fmaf(v.w, v.w, s);
    }
    c2[k] = s;
}

// ---------------------------------------------------------------------------
// Kernel 1: soft = x @ W^T + b, fused split-K-in-block.
// 256 blocks x 1024 threads; 4 K-groups of 256 threads each compute a
// 64x64 partial over K=256; deterministic in-LDS reduce (g=0..3) + bias.
// LDS: tiles (aliased later by partial buffer) = 34 KB.
// ---------------------------------------------------------------------------
__global__ __launch_bounds__(1024, 1) void soft_fused(const float* __restrict__ x,
                                                      const float* __restrict__ W,
                                                      const float* __restrict__ bias,
                                                      float* __restrict__ out_soft) {
    __shared__ float smem[8704];  // 34816 B
    float (*xt)[16][68] = (float (*)[16][68])smem;           // [kg][kk][row]
    float (*wt)[16][68] = (float (*)[16][68])(smem + 4352);  // [kg][kk][col]
    float (*pb)[32][65] = (float (*)[32][65])smem;           // aliases tiles

    const int tid = threadIdx.x;
    const int kg  = tid >> 8;     // K-group 0..3
    const int t   = tid & 255;
    const int r0  = blockIdx.x * 64;
    const int rg  = t >> 4;       // rows rg*4..+3
    const int cg  = t & 15;       // cols cg*4..+3

    float acc[4][4] = {};

    for (int k0 = kg * 256; k0 < kg * 256 + 256; k0 += 16) {
        {
            const int row = t >> 2;          // 0..63 (row == col index for W)
            const int kq  = (t & 3) * 4;     // 0..12
            const float4 v = *(const float4*)(x + (size_t)(r0 + row) * DM + k0 + kq);
            xt[kg][kq + 0][row] = v.x; xt[kg][kq + 1][row] = v.y;
            xt[kg][kq + 2][row] = v.z; xt[kg][kq + 3][row] = v.w;
            const float4 w = *(const float4*)(W + (size_t)row * DM + k0 + kq);
            wt[kg][kq + 0][row] = w.x; wt[kg][kq + 1][row] = w.y;
            wt[kg][kq + 2][row] = w.z; wt[kg][kq + 3][row] = w.w;
        }
        __syncthreads();
#pragma unroll
        for (int kk = 0; kk < 16; ++kk) {
            const float4 xv = *(const float4*)&xt[kg][kk][rg * 4];
            const float4 wv = *(const float4*)&wt[kg][kk][cg * 4];
            const float xa[4] = {xv.x, xv.y, xv.z, xv.w};
            const float wa[4] = {wv.x, wv.y, wv.z, wv.w};
#pragma unroll
            for (int r = 0; r < 4; ++r)
#pragma unroll
                for (int q = 0; q < 4; ++q)
                    acc[r][q] = fmaf(xa[r], wa[q], acc[r][q]);
        }
        __syncthreads();
    }

    // Two rounds (rows 0..31 then 32..63) of partial exchange + reduce
#pragma unroll
    for (int half = 0; half < 2; ++half) {
        if ((rg >> 3) == half) {
#pragma unroll
            for (int r = 0; r < 4; ++r)
                *(float4*)&pb[kg][(rg & 7) * 4 + r][cg * 4] =
                    make_float4(acc[r][0], acc[r][1], acc[r][2], acc[r][3]);
        }
        __syncthreads();
        if (tid < 512) {
            const int row = tid >> 4;     // 0..31
            const int qd  = tid & 15;
            float4 s = *(const float4*)&pb[0][row][qd * 4];
#pragma unroll
            for (int g = 1; g < 4; ++g) {  // fixed ascending order: deterministic
                const float4 v = *(const float4*)&pb[g][row][qd * 4];
                s.x += v.x; s.y += v.y; s.z += v.z; s.w += v.w;
            }
            const float4 bb = *(const float4*)(bias + qd * 4);
            s.x += bb.x; s.y += bb.y; s.z += bb.z; s.w += bb.w;
            *(float4*)(out_soft + (size_t)(r0 + half * 32 + row) * CD + qd * 4) = s;
        }
        __syncthreads();
    }
}

// ---------------------------------------------------------------------------
// Kernel 2: per-row argmin_k of (c2[k] - 2*soft.book_k), register-tiled.
// Thread owns 1 row; 16-code accumulator tile; book/c2 wave-uniform (s_load
// broadcast); soft quad reloaded once per 64 FMAs (L1-hit, amortized).
// grid: (64 row-blocks, NCHUNK code-chunks), 256 threads, ~40 VGPR.
// ---------------------------------------------------------------------------
__global__ __launch_bounds__(256, 4) void dist_argmin3(const float* __restrict__ soft,
                                                       const float* __restrict__ book,
                                                       const float* __restrict__ c2,
                                                       float* __restrict__ cand_d,
                                                       int* __restrict__ cand_i) {
    const int row   = blockIdx.x * 256 + threadIdx.x;
    const int kbase = blockIdx.y * CPC;
    const float4* sp = (const float4*)(soft + (size_t)row * CD);

    float mind = 3.4e38f;
    int   mini = kbase;

    for (int kt = 0; kt < CPC; kt += CTILE) {
        const float4* bp = (const float4*)(book + (size_t)(kbase + kt) * CD);
        float acc[CTILE] = {};
#pragma unroll
        for (int q = 0; q < 16; ++q) {
            const float4 sv = sp[q];
#pragma unroll
            for (int c = 0; c < CTILE; ++c) {
                const float4 bv = bp[(size_t)c * 16 + q];
                acc[c] = fmaf(sv.x, bv.x, acc[c]);
                acc[c] = fmaf(sv.y, bv.y, acc[c]);
                acc[c] = fmaf(sv.z, bv.z, acc[c]);
                acc[c] = fmaf(sv.w, bv.w, acc[c]);
            }
        }
        const int kk0 = kbase + kt;
#pragma unroll
        for (int c = 0; c < CTILE; ++c) {
            const float dd = fmaf(-2.f, acc[c], c2[kk0 + c]);
            // ascending k, strict < -> first-index-wins (matches np.argmin)
            if (dd < mind) { mind = dd; mini = kk0 + c; }
        }
    }

    cand_d[blockIdx.y * M_TOT + row] = mind;
    cand_i[blockIdx.y * M_TOT + row] = mini;
}

// ---------------------------------------------------------------------------
// Kernel 3: combine NCHUNK candidates, gather hard, write idx/ste, losses.
// block = 256 threads = 16 rows x 16 (chunk / dim-quad) lanes
// ---------------------------------------------------------------------------
__global__ __launch_bounds__(256) void finalize(const float* __restrict__ book,
                                                const float* __restrict__ cand_d,
                                                const int* __restrict__ cand_i,
                                                float* __restrict__ out) {
    __shared__ float rd[256];
    __shared__ int   ri[256];
    __shared__ int   ksels[16];
    __shared__ float red[256];

    const int tid  = threadIdx.x;
    const int rloc = tid >> 4;          // 0..15
    const int g    = tid & 15;          // chunk index / dim-quad
    const int row  = blockIdx.x * 16 + rloc;

    rd[tid] = cand_d[(size_t)g * M_TOT + row];
    ri[tid] = cand_i[(size_t)g * M_TOT + row];
    __syncthreads();

    if (g == 0) {
        float bd = rd[rloc * 16];
        int   bi = ri[rloc * 16];
#pragma unroll
        for (int j = 1; j < 16; ++j) {
            const float dd = rd[rloc * 16 + j];
            if (dd < bd) { bd = dd; bi = ri[rloc * 16 + j]; } // ascending chunk => first-wins
        }
        ksels[rloc] = bi;
        out[IDX_OFF + row] = (float)bi;
    }
    __syncthreads();

    const int k  = ksels[rloc];
    const int dq = g * 4;

    const float4 h = *(const float4*)(book + (size_t)k * CD + dq);
    const float4 s = *(const float4*)(out + SOFT_OFF + (size_t)row * CD + dq);

    const float dx = h.x - s.x, dy = h.y - s.y, dz = h.z - s.z, dw = h.w - s.w;
    float4 ste;  // mirror ref expression soft + (hard - soft)
    ste.x = s.x + dx; ste.y = s.y + dy; ste.z = s.z + dz; ste.w = s.w + dw;
    *(float4*)(out + HARD_OFF + (size_t)row * CD + dq) = ste;

    red[tid] = dx * dx + dy * dy + dz * dz + dw * dw;
    __syncthreads();
#pragma unroll
    for (int sh = 128; sh > 0; sh >>= 1) {
        if (tid < sh) red[tid] += red[tid + sh];
        __syncthreads();
    }
    if (tid == 0) {
        const float v = red[0] * (1.0f / (float)(M_TOT * CD));
        atomicAdd(out + LOSS_OFF, v);      // commitment
        atomicAdd(out + LOSS_OFF + 1, v);  // embedding (numerically identical)
    }
}

// ---------------------------------------------------------------------------
extern "C" void kernel_launch(void* const* d_in, const int* in_sizes, int n_in,
                              void* d_out, int out_size, void* d_ws, size_t ws_size,
                              hipStream_t stream) {
    const float* x    = (const float*)d_in[0];
    const float* W    = (const float*)d_in[1];
    const float* bias = (const float*)d_in[2];
    const float* book = (const float*)d_in[3];  // [1][8192][64] == flat [8192][64]
    float* out = (float*)d_out;

    float* ws     = (float*)d_ws;
    float* c2     = ws;                                   // 8192 floats
    float* cand_d = ws + NCODES;                          // NCHUNK*16384 floats
    int*   cand_i = (int*)(cand_d + NCHUNK * M_TOT);      // NCHUNK*16384 ints

    compute_c2<<<NCODES / 256, 256, 0, stream>>>(book, c2);
    soft_fused<<<M_TOT / 64, 1024, 0, stream>>>(x, W, bias, out + SOFT_OFF);
    dist_argmin3<<<dim3(M_TOT / 256, NCHUNK), 256, 0, stream>>>(out + SOFT_OFF, book, c2,
                                                                cand_d, cand_i);
    hipMemsetAsync(out + LOSS_OFF, 0, 2 * sizeof(float), stream);
    finalize<<<M_TOT / 16, 256, 0, stream>>>(book, cand_d, cand_i, out);
}